// Round 3
// baseline (415.633 us; speedup 1.0000x reference)
//
#include <hip/hip_runtime.h>

using i32x4 = __attribute__((ext_vector_type(4))) int;

#define QMAXF 127.0f
#define EPSF 1e-8f

__device__ __forceinline__ void gload_lds16(const void* g, void* l) {
    __builtin_amdgcn_global_load_lds(
        (const __attribute__((address_space(1))) void*)g,
        (__attribute__((address_space(3))) void*)l,
        16, 0, 0);
}

// ---------------- per-row int8 quantization (rows of K=4096 f32) ----------------
// One 256-thread block per row; 16 floats/thread via float4 loads.
__global__ __launch_bounds__(256) void quant_rows_kernel(
    const float* __restrict__ in, signed char* __restrict__ q,
    float* __restrict__ scale, int K) {
    const int row = blockIdx.x;
    const int t = threadIdx.x;
    const float4* rp = reinterpret_cast<const float4*>(in + (size_t)row * K);

    float4 v[4];
#pragma unroll
    for (int j = 0; j < 4; ++j) v[j] = rp[j * 256 + t];

    float amax = 0.f;
#pragma unroll
    for (int j = 0; j < 4; ++j) {
        amax = fmaxf(amax, fabsf(v[j].x));
        amax = fmaxf(amax, fabsf(v[j].y));
        amax = fmaxf(amax, fabsf(v[j].z));
        amax = fmaxf(amax, fabsf(v[j].w));
    }
#pragma unroll
    for (int off = 32; off > 0; off >>= 1)
        amax = fmaxf(amax, __shfl_xor(amax, off));

    __shared__ float red[4];
    if ((t & 63) == 0) red[t >> 6] = amax;
    __syncthreads();
    amax = fmaxf(fmaxf(red[0], red[1]), fmaxf(red[2], red[3]));
    amax = fmaxf(amax, EPSF);
    const float s = amax / QMAXF;   // exactly reference's scale = amax/127
    if (t == 0) scale[row] = s;

    int* qrow = reinterpret_cast<int*>(q + (size_t)row * K);
#pragma unroll
    for (int j = 0; j < 4; ++j) {
        // round-half-even (rintf) to match jnp.round; divide (not mul-by-recip)
        // to match reference x/scale rounding.
        const int b0 = (int)fminf(fmaxf(rintf(v[j].x / s), -128.f), 127.f);
        const int b1 = (int)fminf(fmaxf(rintf(v[j].y / s), -128.f), 127.f);
        const int b2 = (int)fminf(fmaxf(rintf(v[j].z / s), -128.f), 127.f);
        const int b3 = (int)fminf(fmaxf(rintf(v[j].w / s), -128.f), 127.f);
        qrow[j * 256 + t] =
            (b0 & 255) | ((b1 & 255) << 8) | ((b2 & 255) << 16) | ((b3 & 255) << 24);
    }
}

// ---------------- int8 GEMM: out[m][n] = dot(A[m][:], B[n][:]) ----------------
// A = x_q [M][K], B = w_q [N][K] (both K-major), 128x128 tile, BKB=128 bytes,
// 4 waves in 2x2 grid, each wave 64x64 via 4x4 mfma_i32_16x16x64_i8 fragments.
// LDS slot-XOR swizzle (slot ^= row&7) applied on the GLOBAL source address
// (global_load_lds writes linearly) and on the ds_read address (rule #21).
#define BM 128
#define BN 128
#define BKB 128  // K-bytes per stage (2 MFMA k-steps)

__global__ __launch_bounds__(256, 3) void int8_gemm_kernel(
    const signed char* __restrict__ A,  // [M][K]
    const signed char* __restrict__ B,  // [N][K]
    const float* __restrict__ xscale,   // [M]
    const float* __restrict__ wscale,   // [N]
    const float* __restrict__ bias,     // [N]
    float* __restrict__ out,            // [M][N] f32
    int M, int N, int K) {
    __shared__ signed char sA[BM * BKB];  // 16 KiB
    __shared__ signed char sB[BN * BKB];  // 16 KiB

    const int t = threadIdx.x;

    // XCD-aware bijective swizzle (grid divisible by 8)
    const int nwg = gridDim.x;
    const int cpx = nwg >> 3;
    const int swz = (blockIdx.x & 7) * cpx + (blockIdx.x >> 3);
    const int tilesN = N / BN;
    const size_t m0 = (size_t)(swz / tilesN) * BM;
    const size_t n0 = (size_t)(swz % tilesN) * BN;

    // Staging: 4 passes x 16B per thread for each of A,B (256 thr * 16B = 4 KiB/pass)
    const signed char* aSrc[4];
    const signed char* bSrc[4];
    int ldst[4];
#pragma unroll
    for (int p = 0; p < 4; ++p) {
        const int o = p * 4096 + t * 16;   // linear LDS byte offset
        const int row = o >> 7;            // 0..127
        const int slot = (o >> 4) & 7;     // 16B slot within row
        const int gcol = (slot ^ (row & 7)) << 4;  // inverse-swizzled source col
        ldst[p] = o;
        aSrc[p] = A + (m0 + row) * (size_t)K + gcol;
        bSrc[p] = B + (n0 + row) * (size_t)K + gcol;
    }

    const int lane = t & 63;
    const int l15 = lane & 15;
    const int lhi = lane >> 4;  // 0..3
    const int l7 = lane & 7;
    const int wv = t >> 6;
    const int wr = wv >> 1;  // 0..1
    const int wc = wv & 1;   // 0..1

    // Fragment ds_read offsets (swizzled): global slot s=(kk*4+lhi), LDS slot s^row&7
    int aoff[2][4], boff[2][4];
#pragma unroll
    for (int kk = 0; kk < 2; ++kk)
#pragma unroll
        for (int i = 0; i < 4; ++i) {
            const int slot = ((kk << 2) | lhi) ^ l7;  // row&7 == l7 here
            aoff[kk][i] = (wr * 64 + i * 16 + l15) * BKB + (slot << 4);
            boff[kk][i] = (wc * 64 + i * 16 + l15) * BKB + (slot << 4);
        }

    i32x4 acc[4][4];
    const i32x4 zero = {0, 0, 0, 0};
#pragma unroll
    for (int i = 0; i < 4; ++i)
#pragma unroll
        for (int j = 0; j < 4; ++j) acc[i][j] = zero;

    const int ksteps = K / BKB;  // 32
    for (int kt = 0; kt < ksteps; ++kt) {
#pragma unroll
        for (int p = 0; p < 4; ++p) {
            gload_lds16(aSrc[p], sA + ldst[p]);
            gload_lds16(bSrc[p], sB + ldst[p]);
        }
#pragma unroll
        for (int p = 0; p < 4; ++p) { aSrc[p] += BKB; bSrc[p] += BKB; }
        __syncthreads();  // drains vmcnt (global_load_lds) + lgkmcnt
#pragma unroll
        for (int kk = 0; kk < 2; ++kk) {
            i32x4 af[4], bf[4];
#pragma unroll
            for (int i = 0; i < 4; ++i)
                af[i] = *reinterpret_cast<const i32x4*>(sA + aoff[kk][i]);
#pragma unroll
            for (int j = 0; j < 4; ++j)
                bf[j] = *reinterpret_cast<const i32x4*>(sB + boff[kk][j]);
#pragma unroll
            for (int i = 0; i < 4; ++i)
#pragma unroll
                for (int j = 0; j < 4; ++j)
                    acc[i][j] = __builtin_amdgcn_mfma_i32_16x16x64_i8(
                        af[i], bf[j], acc[i][j], 0, 0, 0);
        }
        __syncthreads();  // protect LDS before next stage overwrites
    }

    // Epilogue: C/D layout (16x16): col = lane&15, row = (lane>>4)*4 + reg
#pragma unroll
    for (int i = 0; i < 4; ++i) {
        float xs[4];
#pragma unroll
        for (int r = 0; r < 4; ++r)
            xs[r] = xscale[m0 + wr * 64 + i * 16 + lhi * 4 + r];
#pragma unroll
        for (int j = 0; j < 4; ++j) {
            const int n = (int)n0 + wc * 64 + j * 16 + l15;
            const float wsv = wscale[n];
            const float bv = bias[n];
#pragma unroll
            for (int r = 0; r < 4; ++r) {
                const size_t m = m0 + wr * 64 + i * 16 + lhi * 4 + r;
                out[m * (size_t)N + n] = ((float)acc[i][j][r] * xs[r]) * wsv + bv;
            }
        }
    }
}

extern "C" void kernel_launch(void* const* d_in, const int* in_sizes, int n_in,
                              void* d_out, int out_size, void* d_ws, size_t ws_size,
                              hipStream_t stream) {
    const float* x = (const float*)d_in[0];     // (B,S,I) f32
    const float* w = (const float*)d_in[1];     // (O,I) f32
    const float* bias = (const float*)d_in[2];  // (O,) f32
    float* out = (float*)d_out;

    const int O = in_sizes[2];            // 4096
    const int I = in_sizes[1] / O;        // 4096
    const int M = in_sizes[0] / I;        // 8192 (= B*S)

    // workspace layout (needs ~50.4 MB): x_q | w_q | x_scale | w_scale
    char* ws = (char*)d_ws;
    signed char* xq = (signed char*)ws;
    signed char* wq = xq + (size_t)M * I;
    float* xs = (float*)(wq + (size_t)O * I);
    float* wsc = xs + M;

    quant_rows_kernel<<<M, 256, 0, stream>>>(x, xq, xs, I);
    quant_rows_kernel<<<O, 256, 0, stream>>>(w, wq, wsc, I);

    const int grid = (M / BM) * (O / BN);  // 2048, divisible by 8
    int8_gemm_kernel<<<grid, 256, 0, stream>>>(xq, wq, xs, wsc, bias, out,
                                               M, O, I);
}